// Round 1
// baseline (408.781 us; speedup 1.0000x reference)
//
#include <hip/hip_runtime.h>
#include <math.h>

// ---------------- workspace layout (float offsets) ----------------
#define WS_STATS 0         // 24 floats: [layer][S_r,S_i,S_j,S_k,Q_r,Q_i,Q_j,Q_k]
#define WS_W1    32        // 16*4*9   = 576
#define WS_W2    640       // 64*16*9  = 9216
#define WS_W3    9856      // 128*64*9 = 73728
#define WS_WFC   83584     // 2048*16  = 32768
#define WS_POOL  116352    // 256*200  = 51200
#define WS_IDX   167552    // 256*3 ints
#define WS_OUT1  168448    // 256*16*32*32 = 4194304 (also OUT2)
#define WS_P1    4362752   // 256*16*16*16 = 1048576 (also P2)
#define WS_OUT3  5411328   // 256*128*8*8  = 2097152
#define WS_P3    7508480   // 256*128*4*4  = 524288
// total = 8032768 floats = 30.6 MiB

// Hamilton block table: T[a][b] -> (component, sign)
__device__ const int   d_TC[4][4] = {{0,1,2,3},{1,0,3,2},{2,3,0,1},{3,2,1,0}};
__device__ const float d_TS[4][4] = {{1.f,-1.f,-1.f,-1.f},{1.f,1.f,-1.f,1.f},
                                     {1.f,1.f,1.f,-1.f},{1.f,-1.f,1.f,1.f}};

// ---------------- prep: materialize W1/W2/W3/WFC, zero stats ----------------
__global__ __launch_bounds__(256) void prep_kernel(
    const float* l1r, const float* l1i, const float* l1j, const float* l1k,
    const float* l2r, const float* l2i, const float* l2j, const float* l2k,
    const float* l3r, const float* l3i, const float* l3j, const float* l3k,
    const float* fcr, const float* fci, const float* fcj, const float* fck,
    float* ws)
{
    int tid  = blockIdx.x * 256 + threadIdx.x;
    int nthr = gridDim.x * 256;
    if (tid < 24) ws[WS_STATS + tid] = 0.f;

    { // W1: Cout=16, Cin=4 (Co4=4, Ci4=1)
        const float* cp[4] = {l1r, l1i, l1j, l1k};
        for (int e = tid; e < 576; e += nthr) {
            int oc = e / 36, rem = e % 36, ic = rem / 9, k = rem % 9;
            int p = oc >> 2, o = oc & 3, s = ic;
            ws[WS_W1 + e] = d_TS[p][s] * cp[d_TC[p][s]][o * 9 + k];
        }
    }
    { // W2: Cout=64, Cin=16 (Co4=16, Ci4=4)
        const float* cp[4] = {l2r, l2i, l2j, l2k};
        for (int e = tid; e < 9216; e += nthr) {
            int oc = e / 144, rem = e % 144, ic = rem / 9, k = rem % 9;
            int p = oc >> 4, o = oc & 15, s = ic >> 2, ii = ic & 3;
            ws[WS_W2 + e] = d_TS[p][s] * cp[d_TC[p][s]][(o * 4 + ii) * 9 + k];
        }
    }
    { // W3: Cout=128, Cin=64 (Co4=32, Ci4=16)
        const float* cp[4] = {l3r, l3i, l3j, l3k};
        for (int e = tid; e < 73728; e += nthr) {
            int oc = e / 576, rem = e % 576, ic = rem / 9, k = rem % 9;
            int p = oc >> 5, o = oc & 31, s = ic >> 4, ii = ic & 15;
            ws[WS_W3 + e] = d_TS[p][s] * cp[d_TC[p][s]][(o * 16 + ii) * 9 + k];
        }
    }
    { // WFC: 2048 x 16 from (512,4) components
        const float* cp[4] = {fcr, fci, fcj, fck};
        for (int e = tid; e < 32768; e += nthr) {
            int R = e >> 4, C = e & 15;
            int p = R >> 9, rr = R & 511, q = C >> 2, cc = C & 3;
            ws[WS_WFC + e] = d_TS[q][p] * cp[d_TC[q][p]][rr * 4 + cc];
        }
    }
}

// ---------------- global average pool over 32x32 per (b,c) ----------------
__global__ __launch_bounds__(256) void mean_kernel(const float* __restrict__ x,
                                                   float* __restrict__ pooled)
{
    int bc = blockIdx.x;                    // 256*200
    int t  = threadIdx.x;
    const float4* src = reinterpret_cast<const float4*>(x + (size_t)bc * 1024);
    float4 v = src[t];
    float s = v.x + v.y + v.z + v.w;
    #pragma unroll
    for (int off = 32; off; off >>= 1) s += __shfl_xor(s, off, 64);
    __shared__ float red[4];
    if ((t & 63) == 0) red[t >> 6] = s;
    __syncthreads();
    if (t == 0) pooled[bc] = (red[0] + red[1] + red[2] + red[3]) * (1.0f / 1024.0f);
}

// ---------------- top-3 channels of w*pooled (tie -> lowest idx) ----------------
__global__ __launch_bounds__(64) void topk_kernel(const float* __restrict__ pooled,
                                                  const float* __restrict__ w_eca,
                                                  int* __restrict__ idx3)
{
    int b = blockIdx.x, lane = threadIdx.x;
    float w = w_eca[0];
    float v[4]; int c[4];
    #pragma unroll
    for (int i = 0; i < 4; i++) {
        int ch = lane + 64 * i;
        c[i] = ch;
        v[i] = (ch < 200) ? w * pooled[b * 200 + ch] : -INFINITY;
    }
    for (int k = 0; k < 3; k++) {
        float bv = -INFINITY; int bi = 0x3fffffff;
        #pragma unroll
        for (int i = 0; i < 4; i++)
            if (v[i] > bv || (v[i] == bv && c[i] < bi)) { bv = v[i]; bi = c[i]; }
        for (int off = 32; off; off >>= 1) {
            float ov = __shfl_xor(bv, off, 64);
            int   oi = __shfl_xor(bi, off, 64);
            if (ov > bv || (ov == bv && oi < bi)) { bv = ov; bi = oi; }
        }
        if (lane == 0) idx3[b * 3 + k] = bi;
        #pragma unroll
        for (int i = 0; i < 4; i++) if (c[i] == bi) v[i] = -INFINITY;
    }
}

// ---------------- conv1: gather top3 -> 3x3 conv (4->16ch, 32x32) + stats ----------------
__global__ __launch_bounds__(256) void conv1_kernel(const float* __restrict__ x,
                                                    const int* __restrict__ idx3,
                                                    const float* __restrict__ W1,
                                                    const float* __restrict__ b1,
                                                    float* __restrict__ out1,
                                                    float* __restrict__ stats)
{
    __shared__ float smem[3][34][34];
    int b = blockIdx.x, t = threadIdx.x;
    float* l = &smem[0][0][0];
    for (int i = t; i < 3 * 34 * 34; i += 256) l[i] = 0.f;
    __syncthreads();
    for (int s = 0; s < 3; s++) {
        const float* src = x + ((size_t)b * 200 + idx3[b * 3 + s]) * 1024;
        for (int i = t; i < 1024; i += 256)
            smem[s][(i >> 5) + 1][(i & 31) + 1] = src[i];
    }
    __syncthreads();

    int lane = t & 63;
    int x0 = (t & 7) * 4, y = t >> 3;   // 4 horizontal px per thread
    float acc[16][4];
    #pragma unroll
    for (int oc = 0; oc < 16; oc++) {
        float bb = b1[oc];
        #pragma unroll
        for (int p = 0; p < 4; p++) acc[oc][p] = bb;
    }
    for (int s = 0; s < 3; s++) {
        float n[3][6];
        #pragma unroll
        for (int dy = 0; dy < 3; dy++)
            #pragma unroll
            for (int dx = 0; dx < 6; dx++)
                n[dy][dx] = smem[s][y + dy][x0 + dx];
        #pragma unroll
        for (int oc = 0; oc < 16; oc++) {
            const float* w = W1 + ((oc << 2) + s + 1) * 9;
            float w0=w[0],w1=w[1],w2=w[2],w3=w[3],w4=w[4],w5=w[5],w6=w[6],w7=w[7],w8=w[8];
            #pragma unroll
            for (int p = 0; p < 4; p++) {
                float a = acc[oc][p];
                a = fmaf(w0, n[0][p],   a); a = fmaf(w1, n[0][p+1], a); a = fmaf(w2, n[0][p+2], a);
                a = fmaf(w3, n[1][p],   a); a = fmaf(w4, n[1][p+1], a); a = fmaf(w5, n[1][p+2], a);
                a = fmaf(w6, n[2][p],   a); a = fmaf(w7, n[2][p+1], a); a = fmaf(w8, n[2][p+2], a);
                acc[oc][p] = a;
            }
        }
    }
    float* outb = out1 + (size_t)b * 16 * 1024;
    float s4[4] = {0,0,0,0}, q4[4] = {0,0,0,0};
    #pragma unroll
    for (int oc = 0; oc < 16; oc++) {
        float4 v = make_float4(acc[oc][0], acc[oc][1], acc[oc][2], acc[oc][3]);
        *reinterpret_cast<float4*>(outb + oc * 1024 + y * 32 + x0) = v;
        int g = oc >> 2;
        s4[g] += v.x + v.y + v.z + v.w;
        q4[g] += v.x*v.x + v.y*v.y + v.z*v.z + v.w*v.w;
    }
    #pragma unroll
    for (int g = 0; g < 4; g++) {
        float sv = s4[g], qv = q4[g];
        for (int off = 32; off; off >>= 1) { sv += __shfl_xor(sv, off, 64); qv += __shfl_xor(qv, off, 64); }
        if (lane == 0) { atomicAdd(&stats[g], sv); atomicAdd(&stats[4 + g], qv); }
    }
}

// ---------------- qbn + relu + 2x2 avg pool ----------------
template<int C, int H, int Cq>
__global__ __launch_bounds__(256) void bnpool_kernel(const float* __restrict__ in,
                                                     float* __restrict__ out,
                                                     const float* __restrict__ stats,
                                                     const float* __restrict__ gamma,
                                                     const float* __restrict__ beta,
                                                     float invN)
{
    constexpr int Ho = H / 2;
    int o = blockIdx.x * 256 + threadIdx.x;
    float mean[4]; float var = 0.f;
    #pragma unroll
    for (int g = 0; g < 4; g++) {
        float S = stats[g], Q = stats[4 + g];
        mean[g] = S * invN;
        var += Q - S * S * invN;
    }
    var *= invN;
    float inv = 1.0f / sqrtf(var + 1e-5f);

    int xq = o % Ho;
    int yq = (o / Ho) % Ho;
    int c  = (o / (Ho * Ho)) % C;
    int b  = o / (Ho * Ho * C);
    const float* base = in + ((size_t)((b * C + c) * H + 2 * yq)) * H + 2 * xq;
    float2 v01 = *reinterpret_cast<const float2*>(base);
    float2 v23 = *reinterpret_cast<const float2*>(base + H);
    int g = c / Cq, wv = c % Cq;
    float scale = gamma[wv] * inv;
    float sh = beta[c] - mean[g] * scale;
    float r0 = fmaxf(fmaf(v01.x, scale, sh), 0.f);
    float r1 = fmaxf(fmaf(v01.y, scale, sh), 0.f);
    float r2 = fmaxf(fmaf(v23.x, scale, sh), 0.f);
    float r3 = fmaxf(fmaf(v23.y, scale, sh), 0.f);
    out[o] = 0.25f * (r0 + r1 + r2 + r3);
}

// ---------------- conv2: 16->64 ch, 16x16 + stats ----------------
__global__ __launch_bounds__(256) void conv2_kernel(const float* __restrict__ p1,
                                                    const float* __restrict__ W2,
                                                    const float* __restrict__ b2,
                                                    float* __restrict__ out2,
                                                    float* __restrict__ stats)
{
    __shared__ float smem[16][18][18];
    int b = blockIdx.x, t = threadIdx.x;
    float* l = &smem[0][0][0];
    for (int i = t; i < 16 * 18 * 18; i += 256) l[i] = 0.f;
    __syncthreads();
    const float* src = p1 + (size_t)b * 4096;
    for (int i = t; i < 4096; i += 256)
        smem[i >> 8][((i >> 4) & 15) + 1][(i & 15) + 1] = src[i];
    __syncthreads();

    int lane = t & 63, wv = t >> 6;
    int x0 = (lane & 3) * 4, y = lane >> 2;
    int oc0 = wv * 16;
    float acc[16][4];
    #pragma unroll
    for (int o = 0; o < 16; o++) {
        float bb = b2[oc0 + o];
        #pragma unroll
        for (int p = 0; p < 4; p++) acc[o][p] = bb;
    }
    for (int ic = 0; ic < 16; ic++) {
        float n[3][6];
        #pragma unroll
        for (int dy = 0; dy < 3; dy++)
            #pragma unroll
            for (int dx = 0; dx < 6; dx++)
                n[dy][dx] = smem[ic][y + dy][x0 + dx];
        #pragma unroll
        for (int o = 0; o < 16; o++) {
            const float* w = W2 + ((oc0 + o) * 16 + ic) * 9;
            float w0=w[0],w1=w[1],w2=w[2],w3=w[3],w4=w[4],w5=w[5],w6=w[6],w7=w[7],w8=w[8];
            #pragma unroll
            for (int p = 0; p < 4; p++) {
                float a = acc[o][p];
                a = fmaf(w0, n[0][p],   a); a = fmaf(w1, n[0][p+1], a); a = fmaf(w2, n[0][p+2], a);
                a = fmaf(w3, n[1][p],   a); a = fmaf(w4, n[1][p+1], a); a = fmaf(w5, n[1][p+2], a);
                a = fmaf(w6, n[2][p],   a); a = fmaf(w7, n[2][p+1], a); a = fmaf(w8, n[2][p+2], a);
                acc[o][p] = a;
            }
        }
    }
    float* outb = out2 + (size_t)b * 64 * 256;
    float sv = 0.f, qv = 0.f;
    #pragma unroll
    for (int o = 0; o < 16; o++) {
        float4 v = make_float4(acc[o][0], acc[o][1], acc[o][2], acc[o][3]);
        *reinterpret_cast<float4*>(outb + (oc0 + o) * 256 + y * 16 + x0) = v;
        sv += v.x + v.y + v.z + v.w;
        qv += v.x*v.x + v.y*v.y + v.z*v.z + v.w*v.w;
    }
    for (int off = 32; off; off >>= 1) { sv += __shfl_xor(sv, off, 64); qv += __shfl_xor(qv, off, 64); }
    if (lane == 0) { atomicAdd(&stats[wv], sv); atomicAdd(&stats[4 + wv], qv); }
}

// ---------------- conv3: 64->128 ch, 8x8 + stats (2 blocks/batch) ----------------
__global__ __launch_bounds__(256) void conv3_kernel(const float* __restrict__ p2,
                                                    const float* __restrict__ W3,
                                                    const float* __restrict__ b3,
                                                    float* __restrict__ out3,
                                                    float* __restrict__ stats)
{
    __shared__ float smem[64][10][10];
    int b = blockIdx.x >> 1, half = blockIdx.x & 1, t = threadIdx.x;
    float* l = &smem[0][0][0];
    for (int i = t; i < 64 * 10 * 10; i += 256) l[i] = 0.f;
    __syncthreads();
    const float* src = p2 + (size_t)b * 4096;
    for (int i = t; i < 4096; i += 256)
        smem[i >> 6][((i >> 3) & 7) + 1][(i & 7) + 1] = src[i];
    __syncthreads();

    int lane = t & 63, wv = t >> 6;
    int y = lane >> 3, xx = lane & 7;
    int oc0 = half * 64 + wv * 16;
    float acc[16];
    #pragma unroll
    for (int o = 0; o < 16; o++) acc[o] = b3[oc0 + o];

    for (int ic = 0; ic < 64; ic++) {
        float n[3][3];
        #pragma unroll
        for (int dy = 0; dy < 3; dy++)
            #pragma unroll
            for (int dx = 0; dx < 3; dx++)
                n[dy][dx] = smem[ic][y + dy][xx + dx];
        #pragma unroll
        for (int o = 0; o < 16; o++) {
            const float* w = W3 + ((oc0 + o) * 64 + ic) * 9;
            float a = acc[o];
            a = fmaf(w[0], n[0][0], a); a = fmaf(w[1], n[0][1], a); a = fmaf(w[2], n[0][2], a);
            a = fmaf(w[3], n[1][0], a); a = fmaf(w[4], n[1][1], a); a = fmaf(w[5], n[1][2], a);
            a = fmaf(w[6], n[2][0], a); a = fmaf(w[7], n[2][1], a); a = fmaf(w[8], n[2][2], a);
            acc[o] = a;
        }
    }
    float* outb = out3 + (size_t)b * 128 * 64;
    float sv = 0.f, qv = 0.f;
    #pragma unroll
    for (int o = 0; o < 16; o++) {
        outb[(oc0 + o) * 64 + lane] = acc[o];
        sv += acc[o];
        qv += acc[o] * acc[o];
    }
    int g = oc0 >> 5;
    for (int off = 32; off; off >>= 1) { sv += __shfl_xor(sv, off, 64); qv += __shfl_xor(qv, off, 64); }
    if (lane == 0) { atomicAdd(&stats[g], sv); atomicAdd(&stats[4 + g], qv); }
}

// ---------------- fc: [256,2048] @ [2048,16] + b ----------------
__global__ __launch_bounds__(256) void fc_kernel(const float* __restrict__ p3,
                                                 const float* __restrict__ WFC,
                                                 const float* __restrict__ fcb,
                                                 float* __restrict__ out)
{
    int b = blockIdx.x, t = threadIdx.x;
    int col = t & 15, fr = t >> 4;
    const float* pb = p3 + (size_t)b * 2048;
    float s = 0.f;
    for (int i = 0; i < 128; i++) {
        int f = i * 16 + fr;
        s = fmaf(pb[f], WFC[f * 16 + col], s);
    }
    __shared__ float red[256];
    red[t] = s;
    __syncthreads();
    for (int st = 128; st >= 16; st >>= 1) {
        if (t < st) red[t] += red[t + st];
        __syncthreads();
    }
    if (t < 16) out[b * 16 + t] = red[t] + fcb[t];
}

// ---------------- launch ----------------
extern "C" void kernel_launch(void* const* d_in, const int* in_sizes, int n_in,
                              void* d_out, int out_size, void* d_ws, size_t ws_size,
                              hipStream_t stream)
{
    (void)in_sizes; (void)n_in; (void)out_size; (void)ws_size;
    const float* x     = (const float*)d_in[0];
    const float* w_eca = (const float*)d_in[1];
    const float* l1r = (const float*)d_in[2],  *l1i = (const float*)d_in[3];
    const float* l1j = (const float*)d_in[4],  *l1k = (const float*)d_in[5];
    const float* l1b = (const float*)d_in[6];
    const float* bn1g = (const float*)d_in[7], *bn1b = (const float*)d_in[8];
    const float* l2r = (const float*)d_in[9],  *l2i = (const float*)d_in[10];
    const float* l2j = (const float*)d_in[11], *l2k = (const float*)d_in[12];
    const float* l2b = (const float*)d_in[13];
    const float* bn2g = (const float*)d_in[14], *bn2b = (const float*)d_in[15];
    const float* l3r = (const float*)d_in[16], *l3i = (const float*)d_in[17];
    const float* l3j = (const float*)d_in[18], *l3k = (const float*)d_in[19];
    const float* l3b = (const float*)d_in[20];
    const float* bn3g = (const float*)d_in[21], *bn3b = (const float*)d_in[22];
    const float* fcr = (const float*)d_in[23], *fci = (const float*)d_in[24];
    const float* fcj = (const float*)d_in[25], *fck = (const float*)d_in[26];
    const float* fcb = (const float*)d_in[27];

    float* ws   = (float*)d_ws;
    float* outp = (float*)d_out;

    prep_kernel<<<512, 256, 0, stream>>>(l1r, l1i, l1j, l1k, l2r, l2i, l2j, l2k,
                                         l3r, l3i, l3j, l3k, fcr, fci, fcj, fck, ws);
    mean_kernel<<<51200, 256, 0, stream>>>(x, ws + WS_POOL);
    topk_kernel<<<256, 64, 0, stream>>>(ws + WS_POOL, w_eca, (int*)(ws + WS_IDX));
    conv1_kernel<<<256, 256, 0, stream>>>(x, (const int*)(ws + WS_IDX), ws + WS_W1,
                                          l1b, ws + WS_OUT1, ws + WS_STATS);
    bnpool_kernel<16, 32, 4><<<4096, 256, 0, stream>>>(ws + WS_OUT1, ws + WS_P1,
        ws + WS_STATS, bn1g, bn1b, 1.0f / 1048576.0f);
    conv2_kernel<<<256, 256, 0, stream>>>(ws + WS_P1, ws + WS_W2, l2b,
                                          ws + WS_OUT1, ws + WS_STATS + 8);
    bnpool_kernel<64, 16, 16><<<4096, 256, 0, stream>>>(ws + WS_OUT1, ws + WS_P1,
        ws + WS_STATS + 8, bn2g, bn2b, 1.0f / 1048576.0f);
    conv3_kernel<<<512, 256, 0, stream>>>(ws + WS_P1, ws + WS_W3, l3b,
                                          ws + WS_OUT3, ws + WS_STATS + 16);
    bnpool_kernel<128, 8, 32><<<2048, 256, 0, stream>>>(ws + WS_OUT3, ws + WS_P3,
        ws + WS_STATS + 16, bn3g, bn3b, 1.0f / 524288.0f);
    fc_kernel<<<256, 256, 0, stream>>>(ws + WS_P3, ws + WS_WFC, fcb, outp);
}